// Round 2
// 896.505 us; speedup vs baseline: 1.0426x; 1.0426x over previous
//
#include <hip/hip_runtime.h>

#define DIM   4096
#define NH    32
#define NKV   8
#define HD    128
#define SEQ   2048
#define BATCH 2
#define MROWS (BATCH * SEQ)            // 4096
#define QKVC  (DIM + 2 * NKV * HD)     // 6144

typedef unsigned short u16;
typedef u16   u16x8 __attribute__((ext_vector_type(8)));
typedef u16   u16x4 __attribute__((ext_vector_type(4)));
typedef u16   u16x2 __attribute__((ext_vector_type(2)));
typedef short s16x8 __attribute__((ext_vector_type(8)));
typedef short s16x4 __attribute__((ext_vector_type(4)));
typedef float f32x4 __attribute__((ext_vector_type(4)));

#if __has_builtin(__builtin_amdgcn_mfma_f32_16x16x16bf16_1k)
#define HAVE_MFMA_X16 1
#else
#define HAVE_MFMA_X16 0
#endif

__device__ __forceinline__ u16 f2bf(float f) {
    union { float f; unsigned u; } c; c.f = f;
    unsigned x = c.u;
    x += 0x7fffu + ((x >> 16) & 1u);   // RNE
    return (u16)(x >> 16);
}
__device__ __forceinline__ float bf2f(u16 u) {
    union { unsigned u; float f; } c; c.u = ((unsigned)u) << 16;
    return c.f;
}

// async global->LDS, 16B per lane; LDS dest = wave-uniform base + lane*16
__device__ __forceinline__ void gload16(const u16* g, u16* l) {
    __builtin_amdgcn_global_load_lds(
        (const __attribute__((address_space(1))) unsigned int*)g,
        (__attribute__((address_space(3))) unsigned int*)l, 16, 0, 0);
}

// ---------------------------------------------------------------- prep
__global__ void prep_tables(const float* __restrict__ freqs,
                            float* __restrict__ cos_t, float* __restrict__ sin_t) {
    int i = blockIdx.x * 256 + threadIdx.x;
    if (i < SEQ * (HD / 2)) {
        float f = freqs[i];
        cos_t[i] = __cosf(f);
        sin_t[i] = __sinf(f);
    }
}

__global__ void cvt_x(const float* __restrict__ x, u16* __restrict__ xb) {
    int i = blockIdx.x * 256 + threadIdx.x;   // one float4 per thread
    float4 v = ((const float4*)x)[i];
    u16x4 o = {f2bf(v.x), f2bf(v.y), f2bf(v.z), f2bf(v.w)};
    *(u16x4*)(xb + 4 * (size_t)i) = o;
}

// ---------------------------------------------------------------- weight transpose+convert
// W fp32 [4096][N] row-major  ->  Wt bf16 [N][4096] row-major
__global__ __launch_bounds__(256) void wt_transpose(const float* __restrict__ W,
                                                    u16* __restrict__ Wt, int N) {
    __shared__ float tl[64][65];
    const int n0 = blockIdx.x * 64;
    const int k0 = blockIdx.y * 64;
    const int t  = threadIdx.x;
    {
        const int nl = (t & 15) * 4;
        const int kl = t >> 4;
#pragma unroll
        for (int i = 0; i < 4; i++) {
            float4 v = *(const float4*)(W + (size_t)(k0 + kl + i * 16) * N + n0 + nl);
            tl[kl + i * 16][nl + 0] = v.x;
            tl[kl + i * 16][nl + 1] = v.y;
            tl[kl + i * 16][nl + 2] = v.z;
            tl[kl + i * 16][nl + 3] = v.w;
        }
    }
    __syncthreads();
    {
        const int ks = (t & 15) * 4;
        const int ns = t >> 4;
#pragma unroll
        for (int i = 0; i < 4; i++) {
            int n = ns + i * 16;
            u16x4 o = {f2bf(tl[ks + 0][n]), f2bf(tl[ks + 1][n]),
                       f2bf(tl[ks + 2][n]), f2bf(tl[ks + 3][n])};
            *(u16x4*)(Wt + (size_t)(n0 + n) * DIM + k0 + ks) = o;
        }
    }
}

// ---------------------------------------------------------------- GEMM (m97 structure)
template <bool OUT_BF16>
__global__ __launch_bounds__(256) void gemm_bt(
    const u16* __restrict__ A, const u16* __restrict__ Bt,
    void* __restrict__ Cv, int ldc)
{
    __shared__ u16 lds_a[128 * 32];   // [m][k] contiguous, 64B rows
    __shared__ u16 lds_b[128 * 32];   // [n][k] contiguous

    const int n0 = blockIdx.x * 128;
    const int m0 = blockIdx.y * 128;
    const int t    = threadIdx.x;
    const int wv   = t >> 6;
    const int l    = t & 63;
    const int quad = l >> 4;
    const int l16  = l & 15;
    const int wr   = (wv >> 1) * 64;
    const int wc   = (wv & 1) * 64;

    f32x4 acc[4][4];
#pragma unroll
    for (int mt = 0; mt < 4; mt++)
#pragma unroll
        for (int nt = 0; nt < 4; nt++)
            acc[mt][nt] = (f32x4){0.f, 0.f, 0.f, 0.f};

    const int srow = t >> 2;
    const int scol = (t & 3) * 8;
    const u16* Ag = A  + (size_t)(m0 + srow) * DIM + scol;
    const u16* Bg = Bt + (size_t)(n0 + srow) * DIM + scol;
    u16* la = lds_a + t * 8;
    u16* lb = lds_b + t * 8;

    for (int k0 = 0; k0 < DIM; k0 += 32) {
        gload16(Ag + k0, la);
        gload16(Ag + (size_t)64 * DIM + k0, la + 2048);
        gload16(Bg + k0, lb);
        gload16(Bg + (size_t)64 * DIM + k0, lb + 2048);
        __syncthreads();

        s16x8 af[4], bfr[4];
#pragma unroll
        for (int mt = 0; mt < 4; mt++)
            af[mt] = *(const s16x8*)&lds_a[(wr + mt * 16 + l16) * 32 + quad * 8];
#pragma unroll
        for (int nt = 0; nt < 4; nt++)
            bfr[nt] = *(const s16x8*)&lds_b[(wc + nt * 16 + l16) * 32 + quad * 8];
#pragma unroll
        for (int mt = 0; mt < 4; mt++)
#pragma unroll
            for (int nt = 0; nt < 4; nt++)
                acc[mt][nt] = __builtin_amdgcn_mfma_f32_16x16x32_bf16(af[mt], bfr[nt], acc[mt][nt], 0, 0, 0);

        __syncthreads();
    }

    if (OUT_BF16) {
        u16* C = (u16*)Cv;
#pragma unroll
        for (int mt = 0; mt < 4; mt++)
#pragma unroll
            for (int nt = 0; nt < 4; nt++)
#pragma unroll
                for (int r = 0; r < 4; r++)
                    C[(size_t)(m0 + wr + mt * 16 + quad * 4 + r) * ldc + (n0 + wc + nt * 16 + l16)] =
                        f2bf(acc[mt][nt][r]);
    } else {
        float* C = (float*)Cv;
#pragma unroll
        for (int mt = 0; mt < 4; mt++)
#pragma unroll
            for (int nt = 0; nt < 4; nt++)
#pragma unroll
                for (int r = 0; r < 4; r++)
                    C[(size_t)(m0 + wr + mt * 16 + quad * 4 + r) * ldc + (n0 + wc + nt * 16 + l16)] =
                        acc[mt][nt][r];
    }
}

// ---------------------------------------------------------------- RoPE (in-place on q,k of qkv)
__global__ void rope_kernel(u16* __restrict__ qkv,
                            const float* __restrict__ cos_t, const float* __restrict__ sin_t) {
    int i = blockIdx.x * 256 + threadIdx.x;
    int p   = i & 63;
    int tmp = i >> 6;
    int hh  = tmp % 40;
    int row = tmp / 40;
    int s   = row & (SEQ - 1);
    int col = (hh < 32) ? (hh * HD + 2 * p) : (DIM + (hh - 32) * HD + 2 * p);
    float ct = cos_t[s * 64 + p];
    float st = sin_t[s * 64 + p];
    u16* ptr = qkv + (size_t)row * QKVC + col;
    u16x2 u = *(u16x2*)ptr;
    float x0 = bf2f(u.x), x1 = bf2f(u.y);
    u16x2 o = {f2bf(x0 * ct - x1 * st), f2bf(x0 * st + x1 * ct)};
    *(u16x2*)ptr = o;
}

// ---------------------------------------------------------------- V transpose: qkv v-part -> v_t[b][g][d][s]
__global__ __launch_bounds__(256) void transpose_v(const u16* __restrict__ qkv, u16* __restrict__ v_t) {
    __shared__ u16 tl[64][136];
    const int st = blockIdx.x;
    const int g  = blockIdx.y;
    const int b  = blockIdx.z;
    const int t  = threadIdx.x;
    {
        const int sr = t >> 2, c = t & 3;
        const u16* src = qkv + (size_t)(b * SEQ + st * 64 + sr) * QKVC + DIM + NKV * HD + g * HD;
#pragma unroll
        for (int i = 0; i < 4; i++) {
            int d = (c * 4 + i) * 8;
            *(u16x8*)&tl[sr][d] = *(const u16x8*)(src + d);
        }
    }
    __syncthreads();
    {
        const int dr = t >> 1, c2 = t & 1;
        u16* dst = v_t + ((size_t)((b * NKV + g) * HD) + dr) * SEQ + st * 64;
#pragma unroll
        for (int i = 0; i < 4; i++) {
            int s0 = (c2 * 4 + i) * 8;
            u16x8 o;
#pragma unroll
            for (int j = 0; j < 8; j++) o[j] = tl[s0 + j][dr];
            *(u16x8*)(dst + s0) = o;
        }
    }
}

// ---------------------------------------------------------------- flash attention (non-causal, GQA)
// S^T trick: compute S^T = K·Q^T via mfma(A=K, B=Q). The S^T C-layout
// (lane: q=l16, kv=quad*4+r) IS the A-operand layout of the 16x16x16 MFMA,
// so P = exp(S*scale) stays in registers and feeds PV directly — no LDS
// roundtrip. Row sums become one scalar per lane (q=l16), reduced once in
// the epilogue. No-max softmax (scores statistically bounded, fp32-safe).
//
// v2 pipeline: 8 waves / 128 Q-rows per block (staged K/V feeds 2x compute),
// double-buffered K/V LDS, global->reg loads for tile kt+1 issued BEFORE
// compute(kt) so HBM/L2 latency hides under the MFMA cluster (T14), one
// __syncthreads per tile (was two), setprio(1) around MFMA clusters (T5).
// Race audit: write of buf[cur^1] at iter kt is separated from its last
// reads (iter kt-1) by the barrier at the end of kt-1; read of buf[cur]
// is separated from its write (end of kt-1) by the same barrier.
__global__ __launch_bounds__(512, 4) void attn_kernel(
    const u16* __restrict__ qkv, const u16* __restrict__ v_t, u16* __restrict__ out)
{
    __shared__ u16 lds_k[2][64][136];       // [buf][kv][d]   (+8 pad: b128 reads conflict-min)
    __shared__ u16 lds_vt[2][128][72];      // [buf][d][kv]   (+8 pad: b64 reads conflict-min)
#if !HAVE_MFMA_X16
    __shared__ u16 lds_p[8][16][72];        // fallback P roundtrip
#endif

    const int qt = blockIdx.x, h = blockIdx.y, b = blockIdx.z;
    const int g  = h >> 2;
    const int t  = threadIdx.x;
    const int wv = t >> 6, l = t & 63, quad = l >> 4, l16 = l & 15;
    const float scale = 0.08838834764831845f;   // 1/sqrt(128)

    s16x8 qf[4];
    {
        const size_t qoff = (size_t)(b * SEQ + qt * 128 + wv * 16 + l16) * QKVC + h * HD;
#pragma unroll
        for (int ks = 0; ks < 4; ks++)
            qf[ks] = *(const s16x8*)(qkv + qoff + ks * 32 + quad * 8);
    }

    f32x4 of[8];
#pragma unroll
    for (int no = 0; no < 8; no++) of[no] = (f32x4){0.f, 0.f, 0.f, 0.f};
    float l_part = 0.f;                  // per-lane partial row sum for q = l16

    // staging assignment (512 threads): K tile 64x128 u16, V tile 128x64 u16,
    // 32B (2x u16x8) per thread each.
    const int kr = t >> 3, kc = t & 7;   // K: row 0..63, chunk 0..7 (16 u16 each)
    const int dr = t >> 2, vc = t & 3;   // V: row 0..127, chunk 0..3 (16 u16 each)

    const u16* kg = qkv + (size_t)(b * SEQ + kr) * QKVC + DIM + g * HD + kc * 16;
    const u16* vg = v_t + ((size_t)((b * NKV + g) * HD) + dr) * SEQ + vc * 16;
    const size_t kstep = (size_t)64 * QKVC;  // advance one kv-tile in qkv (u16 elems)

    u16x8 kst0, kst1, vst0, vst1;
    // prologue: load tile 0, write buf 0
    kst0 = *(const u16x8*)(kg);
    kst1 = *(const u16x8*)(kg + 8);
    vst0 = *(const u16x8*)(vg);
    vst1 = *(const u16x8*)(vg + 8);
    kg += kstep; vg += 64;

    *(u16x8*)&lds_k[0][kr][kc * 16]      = kst0;
    *(u16x8*)&lds_k[0][kr][kc * 16 + 8]  = kst1;
    *(u16x8*)&lds_vt[0][dr][vc * 16]     = vst0;
    *(u16x8*)&lds_vt[0][dr][vc * 16 + 8] = vst1;
    __syncthreads();

    for (int kt = 0; kt < SEQ / 64; kt++) {
        const int cur = kt & 1;
        const bool pf = (kt + 1 < SEQ / 64);
        // issue next-tile loads FIRST: in flight across the whole compute phase
        if (pf) {
            kst0 = *(const u16x8*)(kg);
            kst1 = *(const u16x8*)(kg + 8);
            vst0 = *(const u16x8*)(vg);
            vst1 = *(const u16x8*)(vg + 8);
            kg += kstep; vg += 64;
        }

        const u16 (*lk)[136] = lds_k[cur];
        const u16 (*lv)[72]  = lds_vt[cur];

        // S^T = K @ Q^T : tile nt covers kv rows [nt*16, nt*16+16)
        // lane holds S^T[kv = nt*16 + quad*4 + r][q = l16]
        f32x4 sf[4];
#pragma unroll
        for (int nt = 0; nt < 4; nt++) sf[nt] = (f32x4){0.f, 0.f, 0.f, 0.f};
        __builtin_amdgcn_s_setprio(1);
#pragma unroll
        for (int ks = 0; ks < 4; ks++)
#pragma unroll
            for (int nt = 0; nt < 4; nt++) {
                s16x8 kf = *(const s16x8*)&lk[nt * 16 + l16][ks * 32 + quad * 8];
                sf[nt] = __builtin_amdgcn_mfma_f32_16x16x32_bf16(kf, qf[ks], sf[nt], 0, 0, 0);
            }
        __builtin_amdgcn_s_setprio(0);

#if HAVE_MFMA_X16
        // P in registers: A-frag of 16x16x16 (k = quad*4 + j) == S^T C-layout
        s16x4 pfrag[4];
#pragma unroll
        for (int nt = 0; nt < 4; nt++) {
            float p0 = __expf(sf[nt][0] * scale);
            float p1 = __expf(sf[nt][1] * scale);
            float p2 = __expf(sf[nt][2] * scale);
            float p3 = __expf(sf[nt][3] * scale);
            l_part += (p0 + p1) + (p2 + p3);
            pfrag[nt] = (s16x4){(short)f2bf(p0), (short)f2bf(p1),
                                (short)f2bf(p2), (short)f2bf(p3)};
        }

        // O += P @ V  (16x16x16, k-chunk = nt)
        __builtin_amdgcn_s_setprio(1);
#pragma unroll
        for (int no = 0; no < 8; no++)
#pragma unroll
            for (int nt = 0; nt < 4; nt++) {
                s16x4 vf = *(const s16x4*)&lv[no * 16 + l16][nt * 16 + quad * 4];
                of[no] = __builtin_amdgcn_mfma_f32_16x16x16bf16_1k(pfrag[nt], vf, of[no], 0, 0, 0);
            }
        __builtin_amdgcn_s_setprio(0);
#else
        // fallback: P roundtrip through LDS (transpose S^T back while storing)
#pragma unroll
        for (int nt = 0; nt < 4; nt++)
#pragma unroll
            for (int r = 0; r < 4; r++) {
                float p = __expf(sf[nt][r] * scale);
                l_part += p;
                lds_p[wv][l16][nt * 16 + quad * 4 + r] = f2bf(p);
            }
#pragma unroll
        for (int ks2 = 0; ks2 < 2; ks2++) {
            s16x8 pfr = *(const s16x8*)&lds_p[wv][l16][ks2 * 32 + quad * 8];
#pragma unroll
            for (int no = 0; no < 8; no++) {
                s16x8 vfr = *(const s16x8*)&lv[no * 16 + l16][ks2 * 32 + quad * 8];
                of[no] = __builtin_amdgcn_mfma_f32_16x16x32_bf16(pfr, vfr, of[no], 0, 0, 0);
            }
        }
#endif

        // write next tile into the other buffer (compiler inserts the vmcnt
        // wait on the staged regs); reads of that buffer all happened before
        // the barrier at the END of iteration kt-1, so no race.
        if (pf) {
            const int nxt = cur ^ 1;
            *(u16x8*)&lds_k[nxt][kr][kc * 16]      = kst0;
            *(u16x8*)&lds_k[nxt][kr][kc * 16 + 8]  = kst1;
            *(u16x8*)&lds_vt[nxt][dr][vc * 16]     = vst0;
            *(u16x8*)&lds_vt[nxt][dr][vc * 16 + 8] = vst1;
        }
        __syncthreads();
    }

    // epilogue: full row sum for q=l16 = reduce l_part across the 4 quads
    float s = l_part;
    s += __shfl_xor(s, 16);
    s += __shfl_xor(s, 32);
    // O rows are q = quad*4 + r; fetch matching inverse sums
    float il[4];
#pragma unroll
    for (int r = 0; r < 4; r++) il[r] = 1.0f / __shfl(s, quad * 4 + r);

    const size_t ob = (size_t)(b * SEQ + qt * 128 + wv * 16);
#pragma unroll
    for (int no = 0; no < 8; no++)
#pragma unroll
        for (int r = 0; r < 4; r++)
            out[(ob + quad * 4 + r) * (size_t)DIM + h * HD + no * 16 + l16] =
                f2bf(of[no][r] * il[r]);
}

// ---------------------------------------------------------------- launch
extern "C" void kernel_launch(void* const* d_in, const int* in_sizes, int n_in,
                              void* d_out, int out_size, void* d_ws, size_t ws_size,
                              hipStream_t stream)
{
    (void)in_sizes; (void)n_in; (void)out_size; (void)ws_size;
    const float* x     = (const float*)d_in[0];
    const float* freqs = (const float*)d_in[1];
    const float* wq    = (const float*)d_in[2];
    const float* wk    = (const float*)d_in[3];
    const float* wvp   = (const float*)d_in[4];
    const float* wo    = (const float*)d_in[5];

    char* ws = (char*)d_ws;
    float* cos_t = (float*)ws;                                   // 0.5 MB
    float* sin_t = (float*)(ws + 512 * 1024);                    // 0.5 MB
    u16* x_bf    = (u16*)(ws + 1024 * 1024);                     // 33.5 MB
    u16* qkv     = x_bf + (size_t)MROWS * DIM;                   // 50.3 MB
    u16* v_tr    = qkv + (size_t)MROWS * QKVC;                   // 8.4 MB
    u16* attn_o  = v_tr + (size_t)BATCH * NKV * HD * SEQ;        // 33.5 MB
    u16* wt_qkv  = attn_o + (size_t)MROWS * DIM;                 // 50.3 MB
    u16* wt_o    = x_bf;   // aliases x_bf; written only AFTER the qkv GEMM consumed x_bf

    prep_tables<<<512, 256, 0, stream>>>(freqs, cos_t, sin_t);
    cvt_x<<<(MROWS * DIM) / (4 * 256), 256, 0, stream>>>(x, x_bf);

    wt_transpose<<<dim3(DIM / 64, DIM / 64), 256, 0, stream>>>(wq, wt_qkv, DIM);
    wt_transpose<<<dim3((NKV * HD) / 64, DIM / 64), 256, 0, stream>>>(wk, wt_qkv + (size_t)DIM * DIM, NKV * HD);
    wt_transpose<<<dim3((NKV * HD) / 64, DIM / 64), 256, 0, stream>>>(wvp, wt_qkv + (size_t)(DIM + NKV * HD) * DIM, NKV * HD);

    gemm_bt<true><<<dim3(QKVC / 128, MROWS / 128), 256, 0, stream>>>(x_bf, wt_qkv, qkv, QKVC);

    wt_transpose<<<dim3(DIM / 64, DIM / 64), 256, 0, stream>>>(wo, wt_o, DIM);

    rope_kernel<<<(MROWS * 40 * 64) / 256, 256, 0, stream>>>(qkv, cos_t, sin_t);
    transpose_v<<<dim3(SEQ / 64, NKV, BATCH), 256, 0, stream>>>(qkv, v_tr);
    attn_kernel<<<dim3(SEQ / 128, NH, BATCH), 512, 0, stream>>>(qkv, v_tr, attn_o);

    gemm_bt<false><<<dim3(DIM / 128, MROWS / 128), 256, 0, stream>>>(attn_o, wt_o, d_out, DIM);
}

// Round 4
// 857.440 us; speedup vs baseline: 1.0901x; 1.0456x over previous
//
#include <hip/hip_runtime.h>

#define DIM   4096
#define NH    32
#define NKV   8
#define HD    128
#define SEQ   2048
#define BATCH 2
#define MROWS (BATCH * SEQ)            // 4096
#define QKVC  (DIM + 2 * NKV * HD)     // 6144

typedef unsigned short u16;
typedef u16   u16x8 __attribute__((ext_vector_type(8)));
typedef u16   u16x4 __attribute__((ext_vector_type(4)));
typedef u16   u16x2 __attribute__((ext_vector_type(2)));
typedef short s16x8 __attribute__((ext_vector_type(8)));
typedef short s16x4 __attribute__((ext_vector_type(4)));
typedef float f32x4 __attribute__((ext_vector_type(4)));
typedef float f32x16 __attribute__((ext_vector_type(16)));
typedef unsigned u32x4 __attribute__((ext_vector_type(4)));

__device__ __forceinline__ u16 f2bf(float f) {
    union { float f; unsigned u; } c; c.f = f;
    unsigned x = c.u;
    x += 0x7fffu + ((x >> 16) & 1u);   // RNE
    return (u16)(x >> 16);
}
__device__ __forceinline__ float bf2f(u16 u) {
    union { unsigned u; float f; } c; c.u = ((unsigned)u) << 16;
    return c.f;
}
// pack two floats into one u32 of 2x bf16 (lo = a, hi = b)
__device__ __forceinline__ unsigned pack2bf(float a, float b) {
    return ((unsigned)f2bf(b) << 16) | (unsigned)f2bf(a);
}

// async global->LDS, 16B per lane; LDS dest = wave-uniform base + lane*16
__device__ __forceinline__ void gload16(const u16* g, u16* l) {
    __builtin_amdgcn_global_load_lds(
        (const __attribute__((address_space(1))) unsigned int*)g,
        (__attribute__((address_space(3))) unsigned int*)l, 16, 0, 0);
}

// ---------------------------------------------------------------- prep
__global__ void prep_tables(const float* __restrict__ freqs,
                            float* __restrict__ cos_t, float* __restrict__ sin_t) {
    int i = blockIdx.x * 256 + threadIdx.x;
    if (i < SEQ * (HD / 2)) {
        float f = freqs[i];
        cos_t[i] = __cosf(f);
        sin_t[i] = __sinf(f);
    }
}

__global__ void cvt_x(const float* __restrict__ x, u16* __restrict__ xb) {
    int i = blockIdx.x * 256 + threadIdx.x;   // one float4 per thread
    float4 v = ((const float4*)x)[i];
    u16x4 o = {f2bf(v.x), f2bf(v.y), f2bf(v.z), f2bf(v.w)};
    *(u16x4*)(xb + 4 * (size_t)i) = o;
}

// ---------------------------------------------------------------- weight transpose+convert
// W fp32 [4096][N] row-major  ->  Wt bf16 [N][4096] row-major
__global__ __launch_bounds__(256) void wt_transpose(const float* __restrict__ W,
                                                    u16* __restrict__ Wt, int N) {
    __shared__ float tl[64][65];
    const int n0 = blockIdx.x * 64;
    const int k0 = blockIdx.y * 64;
    const int t  = threadIdx.x;
    {
        const int nl = (t & 15) * 4;
        const int kl = t >> 4;
#pragma unroll
        for (int i = 0; i < 4; i++) {
            float4 v = *(const float4*)(W + (size_t)(k0 + kl + i * 16) * N + n0 + nl);
            tl[kl + i * 16][nl + 0] = v.x;
            tl[kl + i * 16][nl + 1] = v.y;
            tl[kl + i * 16][nl + 2] = v.z;
            tl[kl + i * 16][nl + 3] = v.w;
        }
    }
    __syncthreads();
    {
        const int ks = (t & 15) * 4;
        const int ns = t >> 4;
#pragma unroll
        for (int i = 0; i < 4; i++) {
            int n = ns + i * 16;
            u16x4 o = {f2bf(tl[ks + 0][n]), f2bf(tl[ks + 1][n]),
                       f2bf(tl[ks + 2][n]), f2bf(tl[ks + 3][n])};
            *(u16x4*)(Wt + (size_t)(n0 + n) * DIM + k0 + ks) = o;
        }
    }
}

// ---------------------------------------------------------------- GEMM (m97 structure)
template <bool OUT_BF16>
__global__ __launch_bounds__(256) void gemm_bt(
    const u16* __restrict__ A, const u16* __restrict__ Bt,
    void* __restrict__ Cv, int ldc)
{
    __shared__ u16 lds_a[128 * 32];   // [m][k] contiguous, 64B rows
    __shared__ u16 lds_b[128 * 32];   // [n][k] contiguous

    const int n0 = blockIdx.x * 128;
    const int m0 = blockIdx.y * 128;
    const int t    = threadIdx.x;
    const int wv   = t >> 6;
    const int l    = t & 63;
    const int quad = l >> 4;
    const int l16  = l & 15;
    const int wr   = (wv >> 1) * 64;
    const int wc   = (wv & 1) * 64;

    f32x4 acc[4][4];
#pragma unroll
    for (int mt = 0; mt < 4; mt++)
#pragma unroll
        for (int nt = 0; nt < 4; nt++)
            acc[mt][nt] = (f32x4){0.f, 0.f, 0.f, 0.f};

    const int srow = t >> 2;
    const int scol = (t & 3) * 8;
    const u16* Ag = A  + (size_t)(m0 + srow) * DIM + scol;
    const u16* Bg = Bt + (size_t)(n0 + srow) * DIM + scol;
    u16* la = lds_a + t * 8;
    u16* lb = lds_b + t * 8;

    for (int k0 = 0; k0 < DIM; k0 += 32) {
        gload16(Ag + k0, la);
        gload16(Ag + (size_t)64 * DIM + k0, la + 2048);
        gload16(Bg + k0, lb);
        gload16(Bg + (size_t)64 * DIM + k0, lb + 2048);
        __syncthreads();

        s16x8 af[4], bfr[4];
#pragma unroll
        for (int mt = 0; mt < 4; mt++)
            af[mt] = *(const s16x8*)&lds_a[(wr + mt * 16 + l16) * 32 + quad * 8];
#pragma unroll
        for (int nt = 0; nt < 4; nt++)
            bfr[nt] = *(const s16x8*)&lds_b[(wc + nt * 16 + l16) * 32 + quad * 8];
#pragma unroll
        for (int mt = 0; mt < 4; mt++)
#pragma unroll
            for (int nt = 0; nt < 4; nt++)
                acc[mt][nt] = __builtin_amdgcn_mfma_f32_16x16x32_bf16(af[mt], bfr[nt], acc[mt][nt], 0, 0, 0);

        __syncthreads();
    }

    if (OUT_BF16) {
        u16* C = (u16*)Cv;
#pragma unroll
        for (int mt = 0; mt < 4; mt++)
#pragma unroll
            for (int nt = 0; nt < 4; nt++)
#pragma unroll
                for (int r = 0; r < 4; r++)
                    C[(size_t)(m0 + wr + mt * 16 + quad * 4 + r) * ldc + (n0 + wc + nt * 16 + l16)] =
                        f2bf(acc[mt][nt][r]);
    } else {
        float* C = (float*)Cv;
#pragma unroll
        for (int mt = 0; mt < 4; mt++)
#pragma unroll
            for (int nt = 0; nt < 4; nt++)
#pragma unroll
                for (int r = 0; r < 4; r++)
                    C[(size_t)(m0 + wr + mt * 16 + quad * 4 + r) * ldc + (n0 + wc + nt * 16 + l16)] =
                        acc[mt][nt][r];
    }
}

// ---------------------------------------------------------------- RoPE (in-place on q,k of qkv)
__global__ void rope_kernel(u16* __restrict__ qkv,
                            const float* __restrict__ cos_t, const float* __restrict__ sin_t) {
    int i = blockIdx.x * 256 + threadIdx.x;
    int p   = i & 63;
    int tmp = i >> 6;
    int hh  = tmp % 40;
    int row = tmp / 40;
    int s   = row & (SEQ - 1);
    int col = (hh < 32) ? (hh * HD + 2 * p) : (DIM + (hh - 32) * HD + 2 * p);
    float ct = cos_t[s * 64 + p];
    float st = sin_t[s * 64 + p];
    u16* ptr = qkv + (size_t)row * QKVC + col;
    u16x2 u = *(u16x2*)ptr;
    float x0 = bf2f(u.x), x1 = bf2f(u.y);
    u16x2 o = {f2bf(x0 * ct - x1 * st), f2bf(x0 * st + x1 * ct)};
    *(u16x2*)ptr = o;
}

// ---------------------------------------------------------------- V transpose: qkv v-part -> v_t[b][g][d][s]
__global__ __launch_bounds__(256) void transpose_v(const u16* __restrict__ qkv, u16* __restrict__ v_t) {
    __shared__ u16 tl[64][136];
    const int st = blockIdx.x;
    const int g  = blockIdx.y;
    const int b  = blockIdx.z;
    const int t  = threadIdx.x;
    {
        const int sr = t >> 2, c = t & 3;
        const u16* src = qkv + (size_t)(b * SEQ + st * 64 + sr) * QKVC + DIM + NKV * HD + g * HD;
#pragma unroll
        for (int i = 0; i < 4; i++) {
            int d = (c * 4 + i) * 8;
            *(u16x8*)&tl[sr][d] = *(const u16x8*)(src + d);
        }
    }
    __syncthreads();
    {
        const int dr = t >> 1, c2 = t & 1;
        u16* dst = v_t + ((size_t)((b * NKV + g) * HD) + dr) * SEQ + st * 64;
#pragma unroll
        for (int i = 0; i < 4; i++) {
            int s0 = (c2 * 4 + i) * 8;
            u16x8 o;
#pragma unroll
            for (int j = 0; j < 8; j++) o[j] = tl[s0 + j][dr];
            *(u16x8*)(dst + s0) = o;
        }
    }
}

// ---------------------------------------------------------------- flash attention (non-causal, GQA)
// v3: 32x32x16 MFMA throughout (full-rate PV), 32 Q-rows per wave,
// 4 waves / 128 Q-rows per block, fragment-major LDS layouts so every
// ds_read_b128 / ds_write_b128 is lane-sequential (bank-conflict-free).
//
// S^T trick at 32x32: S^T = K @ Q^T via mfma(A=K, B=Q^T). C-layout:
// col = q = lane&31, row = kv_local = (reg&3)+8*(reg>>2)+4*(lane>>5).
// PV A-frag (lane: row=q=lane&31, k = (lane>>5)*8+j) needs a half-lane
// (lane ^ 32) exchange of packed bf16 pairs -> pack2bf + shfl_xor(32).
// Row sums: every P value a lane holds shares q=lane&31 -> one
// shfl_xor(32) gives the full denominator.
__global__ __launch_bounds__(256, 2) void attn_kernel(
    const u16* __restrict__ qkv, const u16* __restrict__ v_t, u16* __restrict__ out)
{
    // fragment-major: K[chunk c=d>>3][kv][8] ; V[chunk c2=kv>>3][d][8]
    __shared__ u16 lds_k[2][16 * 64 * 8];    // 16 KB per buf
    __shared__ u16 lds_v[2][8 * 128 * 8];    // 16 KB per buf

    const int qt = blockIdx.x, head = blockIdx.y, b = blockIdx.z;
    const int g  = head >> 2;
    const int t  = threadIdx.x;
    const int wv = t >> 6, l = t & 63, l31 = l & 31, hl = l >> 5;
    const float scale2 = 0.08838834764831845f * 1.44269504088896341f; // 1/sqrt(128)*log2(e)

    // Q fragments (B-operand): lane holds Q[q=l31][d = ks*16 + hl*8 + j]
    s16x8 qf[8];
    {
        const u16* qp = qkv + (size_t)(b * SEQ + qt * 128 + wv * 32 + l31) * QKVC
                      + head * HD + hl * 8;
#pragma unroll
        for (int ks = 0; ks < 8; ks++)
            qf[ks] = *(const s16x8*)(qp + ks * 16);
    }

    f32x16 of[4];
#pragma unroll
    for (int dt = 0; dt < 4; dt++)
#pragma unroll
        for (int r = 0; r < 16; r++) of[dt][r] = 0.f;
    float l_part = 0.f;

    // staging (256 threads, 64 B per thread per tile for each of K and V)
    const int kv_s = t >> 2, cp = t & 3;     // K: row kv, 64B col chunk
    const int d_s  = t >> 1, sc = t & 1;     // V: row d, 64B s chunk
    const u16* kg = qkv + (size_t)(b * SEQ + kv_s) * QKVC + DIM + g * HD + cp * 32;
    const u16* vg = v_t + ((size_t)((b * NKV + g) * HD) + d_s) * SEQ + sc * 32;
    const size_t kstep = (size_t)64 * QKVC;

    u16x8 kst[4], vst[4];
#pragma unroll
    for (int i = 0; i < 4; i++) kst[i] = *(const u16x8*)(kg + i * 8);
#pragma unroll
    for (int i = 0; i < 4; i++) vst[i] = *(const u16x8*)(vg + i * 8);
    kg += kstep; vg += 64;

#pragma unroll
    for (int i = 0; i < 4; i++) {
        *(u16x8*)&lds_k[0][((cp * 4 + i) * 64 + kv_s) * 8] = kst[i];
        *(u16x8*)&lds_v[0][((sc * 4 + i) * 128 + d_s) * 8] = vst[i];
    }
    __syncthreads();

    for (int kt = 0; kt < SEQ / 64; kt++) {
        const int cur = kt & 1;
        const bool pf = (kt + 1 < SEQ / 64);
        if (pf) {   // issue next-tile loads first: in flight across compute
#pragma unroll
            for (int i = 0; i < 4; i++) kst[i] = *(const u16x8*)(kg + i * 8);
#pragma unroll
            for (int i = 0; i < 4; i++) vst[i] = *(const u16x8*)(vg + i * 8);
            kg += kstep; vg += 64;
        }
        const u16* lk = lds_k[cur];
        const u16* lv = lds_v[cur];

        // S^T = K @ Q^T : two 32x32 tiles (m = kv half of the 64-tile)
        f32x16 sf[2];
#pragma unroll
        for (int m = 0; m < 2; m++)
#pragma unroll
            for (int r = 0; r < 16; r++) sf[m][r] = 0.f;

        __builtin_amdgcn_s_setprio(1);
#pragma unroll
        for (int ks = 0; ks < 8; ks++)
#pragma unroll
            for (int m = 0; m < 2; m++) {
                s16x8 kf = *(const s16x8*)&lk[((ks * 2 + hl) * 64 + m * 32 + l31) * 8];
                sf[m] = __builtin_amdgcn_mfma_f32_32x32x16_bf16(kf, qf[ks], sf[m], 0, 0, 0);
            }
        __builtin_amdgcn_s_setprio(0);

        // softmax (no-max) + pack into PV A-frags.
        // lane (hl) owns kv_local = (r&3)+8*(r>>2)+4*hl within each 32-block;
        // packed pairs pk[i] = (p[2i], p[2i+1]); partner's pairs via shfl_xor(32).
        s16x8 pfrag[4];                       // kv 16-chunks c = m*2 + c16
#pragma unroll
        for (int m = 0; m < 2; m++) {
            float p[16];
#pragma unroll
            for (int r = 0; r < 16; r++) {
                p[r] = exp2f(sf[m][r] * scale2);
                l_part += p[r];
            }
            unsigned pk[8];
#pragma unroll
            for (int i = 0; i < 8; i++)
                pk[i] = pack2bf(p[2 * i], p[2 * i + 1]);
            unsigned sx[8];
#pragma unroll
            for (int i = 0; i < 8; i++) sx[i] = (unsigned)__shfl_xor((int)pk[i], 32);
            // A-frag words: frag(c16) needs kv_local = c16*16 + hl*8 + j
            unsigned w0 = hl ? sx[2] : pk[0];
            unsigned w1 = hl ? sx[3] : pk[1];
            unsigned w2 = hl ? pk[2] : sx[0];
            unsigned w3 = hl ? pk[3] : sx[1];
            unsigned w4 = hl ? sx[6] : pk[4];
            unsigned w5 = hl ? sx[7] : pk[5];
            unsigned w6 = hl ? pk[6] : sx[4];
            unsigned w7 = hl ? pk[7] : sx[5];
            u32x4 lo4 = {w0, w1, w2, w3};
            u32x4 hi4 = {w4, w5, w6, w7};
            pfrag[m * 2 + 0] = *(s16x8*)&lo4;
            pfrag[m * 2 + 1] = *(s16x8*)&hi4;
        }

        // O += P @ V  (full-rate 32x32x16)
        __builtin_amdgcn_s_setprio(1);
#pragma unroll
        for (int c = 0; c < 4; c++)
#pragma unroll
            for (int dt = 0; dt < 4; dt++) {
                s16x8 vf = *(const s16x8*)&lv[((c * 2 + hl) * 128 + dt * 32 + l31) * 8];
                of[dt] = __builtin_amdgcn_mfma_f32_32x32x16_bf16(pfrag[c], vf, of[dt], 0, 0, 0);
            }
        __builtin_amdgcn_s_setprio(0);

        if (pf) {
            const int nxt = cur ^ 1;
#pragma unroll
            for (int i = 0; i < 4; i++) {
                *(u16x8*)&lds_k[nxt][((cp * 4 + i) * 64 + kv_s) * 8] = kst[i];
                *(u16x8*)&lds_v[nxt][((sc * 4 + i) * 128 + d_s) * 8] = vst[i];
            }
        }
        __syncthreads();
    }

    // epilogue: full denominator for q=l31, then normalize+store
    float tot = l_part + __shfl_xor(l_part, 32);
    const size_t ob = (size_t)(b * SEQ + qt * 128 + wv * 32);
#pragma unroll
    for (int r = 0; r < 16; r++) {
        const int qrow = (r & 3) + 8 * (r >> 2) + 4 * hl;
        const float il = 1.0f / __shfl(tot, qrow);
#pragma unroll
        for (int dt = 0; dt < 4; dt++)
            out[(ob + qrow) * (size_t)DIM + head * HD + dt * 32 + l31] =
                f2bf(of[dt][r] * il);
    }
}

// ---------------------------------------------------------------- launch
extern "C" void kernel_launch(void* const* d_in, const int* in_sizes, int n_in,
                              void* d_out, int out_size, void* d_ws, size_t ws_size,
                              hipStream_t stream)
{
    (void)in_sizes; (void)n_in; (void)out_size; (void)ws_size;
    const float* x     = (const float*)d_in[0];
    const float* freqs = (const float*)d_in[1];
    const float* wq    = (const float*)d_in[2];
    const float* wk    = (const float*)d_in[3];
    const float* wvp   = (const float*)d_in[4];
    const float* wo    = (const float*)d_in[5];

    char* ws = (char*)d_ws;
    float* cos_t = (float*)ws;                                   // 0.5 MB
    float* sin_t = (float*)(ws + 512 * 1024);                    // 0.5 MB
    u16* x_bf    = (u16*)(ws + 1024 * 1024);                     // 33.5 MB
    u16* qkv     = x_bf + (size_t)MROWS * DIM;                   // 50.3 MB
    u16* v_tr    = qkv + (size_t)MROWS * QKVC;                   // 8.4 MB
    u16* attn_o  = v_tr + (size_t)BATCH * NKV * HD * SEQ;        // 33.5 MB
    u16* wt_qkv  = attn_o + (size_t)MROWS * DIM;                 // 50.3 MB
    u16* wt_o    = x_bf;   // aliases x_bf; written only AFTER the qkv GEMM consumed x_bf

    prep_tables<<<512, 256, 0, stream>>>(freqs, cos_t, sin_t);
    cvt_x<<<(MROWS * DIM) / (4 * 256), 256, 0, stream>>>(x, x_bf);

    wt_transpose<<<dim3(DIM / 64, DIM / 64), 256, 0, stream>>>(wq, wt_qkv, DIM);
    wt_transpose<<<dim3((NKV * HD) / 64, DIM / 64), 256, 0, stream>>>(wk, wt_qkv + (size_t)DIM * DIM, NKV * HD);
    wt_transpose<<<dim3((NKV * HD) / 64, DIM / 64), 256, 0, stream>>>(wvp, wt_qkv + (size_t)(DIM + NKV * HD) * DIM, NKV * HD);

    gemm_bt<true><<<dim3(QKVC / 128, MROWS / 128), 256, 0, stream>>>(x_bf, wt_qkv, qkv, QKVC);

    wt_transpose<<<dim3(DIM / 64, DIM / 64), 256, 0, stream>>>(wo, wt_o, DIM);

    rope_kernel<<<(MROWS * 40 * 64) / 256, 256, 0, stream>>>(qkv, cos_t, sin_t);
    transpose_v<<<dim3(SEQ / 64, NKV, BATCH), 256, 0, stream>>>(qkv, v_tr);
    attn_kernel<<<dim3(SEQ / 128, NH, BATCH), 256, 0, stream>>>(qkv, v_tr, attn_o);

    gemm_bt<false><<<dim3(DIM / 128, MROWS / 128), 256, 0, stream>>>(attn_o, wt_o, d_out, DIM);
}